// Round 2
// baseline (128.625 us; speedup 1.0000x reference)
//
#include <hip/hip_runtime.h>
#include <hip/hip_bf16.h>

// Problem constants (fixed by setup_inputs)
#define B 4
#define T 1024
#define D 512
#define U 32
#define WIN 64           // attention window size (j in [t-32, t+31])
#define EPS 1e-7f

// ---------------------------------------------------------------------------
// Kernel A: qk[row][0:32]  = x[row,:] @ Wt + bh   (q with bias folded)
//           qk[row][32:64] = x[row,:] @ Wx        (k)
// One wave per row; lane u (<32 -> Wt col u, >=32 -> Wx col u-32).
// x row staged in LDS; LDS reads are same-address broadcast (free).
// ---------------------------------------------------------------------------
__global__ __launch_bounds__(256) void qk_kernel(
    const float* __restrict__ x, const float* __restrict__ Wt,
    const float* __restrict__ Wx, const float* __restrict__ bh,
    float* __restrict__ qk)
{
    const int lane = threadIdx.x & 63;
    const int wv   = threadIdx.x >> 6;
    const int row  = blockIdx.x * 4 + wv;      // 0 .. B*T-1

    __shared__ float xrow[4][D];
    const float* xr = x + (size_t)row * D;
    #pragma unroll
    for (int i = 0; i < D / 64; ++i)
        xrow[wv][lane + i * 64] = xr[lane + i * 64];
    __syncthreads();

    const float* W = (lane < U) ? Wt : Wx;
    const int u = lane & (U - 1);
    float acc = (lane < U) ? bh[u] : 0.0f;

    #pragma unroll 8
    for (int d = 0; d < D; ++d)
        acc += xrow[wv][d] * W[d * U + u];

    qk[(size_t)row * WIN + lane] = acc;
}

// ---------------------------------------------------------------------------
// Kernel B: one wave per (b,t).
// Phase 1: lane j owns window pos jj = t-32+j; computes
//          e_j = exp( ba + sum_u Wa[u]*tanh(q[t,u]+k[jj,u]) ), 0 if jj OOB.
//          Wave shuffle-reduce -> s; a_j = e_j/(s+EPS).
// Phase 2: lanes switch to owning d columns (2 x float4 per lane),
//          loop j over valid window, broadcast a_j via shfl, FMA rows of x.
// ---------------------------------------------------------------------------
__global__ __launch_bounds__(256) void attn_kernel(
    const float* __restrict__ x, const float* __restrict__ qk,
    const float* __restrict__ Wa, const float* __restrict__ ba,
    float* __restrict__ out)
{
    const int lane = threadIdx.x & 63;
    const int wv   = threadIdx.x >> 6;
    const int gt   = blockIdx.x * 4 + wv;      // 0 .. B*T-1
    const int b    = gt >> 10;                 // / T
    const int t    = gt & (T - 1);

    const float* qrow = qk + (size_t)gt * WIN;

    // ---- Phase 1: scores ----
    const int jj = t - 32 + lane;
    const bool valid = (jj >= 0) && (jj < T);
    float e = 0.0f;
    if (valid) {
        const float* krow = qk + ((size_t)(b * T + jj) * WIN) + U;
        float acc = ba[0];
        #pragma unroll
        for (int u = 0; u < U; ++u)
            acc += Wa[u] * tanhf(qrow[u] + krow[u]);
        e = __expf(acc);
    }

    float s = e;
    #pragma unroll
    for (int off = 32; off > 0; off >>= 1)
        s += __shfl_xor(s, off);
    const float a = e / (s + EPS);

    // ---- Phase 2: weighted sum of x rows ----
    const int j0 = (t < 32) ? (32 - t) : 0;              // first valid j
    const int j1 = (T + 32 - t < WIN) ? (T + 32 - t) : WIN; // one past last

    float4 v0 = make_float4(0.f, 0.f, 0.f, 0.f);
    float4 v1 = make_float4(0.f, 0.f, 0.f, 0.f);
    const float* xb = x + (size_t)b * T * D;

    for (int j = j0; j < j1; ++j) {
        const float aj = __shfl(a, j);
        const float* xr = xb + (size_t)(t - 32 + j) * D;
        const float4 xv0 = ((const float4*)xr)[lane];
        const float4 xv1 = ((const float4*)xr)[lane + 64];
        v0.x += aj * xv0.x; v0.y += aj * xv0.y;
        v0.z += aj * xv0.z; v0.w += aj * xv0.w;
        v1.x += aj * xv1.x; v1.y += aj * xv1.y;
        v1.z += aj * xv1.z; v1.w += aj * xv1.w;
    }

    float* orow = out + (size_t)gt * D;
    ((float4*)orow)[lane]      = v0;
    ((float4*)orow)[lane + 64] = v1;
}

extern "C" void kernel_launch(void* const* d_in, const int* in_sizes, int n_in,
                              void* d_out, int out_size, void* d_ws, size_t ws_size,
                              hipStream_t stream)
{
    const float* x  = (const float*)d_in[0];
    const float* Wt = (const float*)d_in[1];
    const float* Wx = (const float*)d_in[2];
    const float* bh = (const float*)d_in[3];
    const float* Wa = (const float*)d_in[4];
    const float* ba = (const float*)d_in[5];
    float* out = (float*)d_out;
    float* qk  = (float*)d_ws;   // B*T*64 floats = 1 MB

    const int rows = B * T;                 // 4096
    dim3 blk(256);
    dim3 grdA(rows / 4);                    // 1024 blocks, 4 rows each
    qk_kernel<<<grdA, blk, 0, stream>>>(x, Wt, Wx, bh, qk);

    dim3 grdB(rows / 4);                    // 1024 blocks, 1 wave per (b,t)
    attn_kernel<<<grdB, blk, 0, stream>>>(x, qk, Wa, ba, out);
}